// Round 4
// baseline (73.694 us; speedup 1.0000x reference)
//
#include <hip/hip_runtime.h>

// Problem constants (match reference file)
#define KK   3
#define Bn   8
#define Cn   64
#define Hn   128
#define Wn   128
#define NTAP 9

// Blocking
#define BAND  8                 // output rows per block
#define CHB   4                 // channels per block
#define ROWS  15                // BAND-1 + floor(2*3.0) + 1 (bilinear r1)
#define NBANDS (Hn / BAND)      // 16
#define NCG    (Cn / CHB)       // 16

__global__ __launch_bounds__(256) void dyn_unfold_kernel(
    const float* __restrict__ x,      // (B, C, H, W)
    const float* __restrict__ dmap,   // (B, 1, H, W)
    float* __restrict__ out)          // (B, C*9, H*W)
{
    __shared__ float lds[CHB][ROWS][Wn];   // 4*15*128*4B = 30 KB

    const int bid  = blockIdx.x;
    const int cg   = bid & (NCG - 1);          // channel group (fastest)
    const int band = (bid >> 4) & (NBANDS - 1);
    const int b    = bid >> 8;

    const int oh0 = band * BAND;
    const int tid = threadIdx.x;

    // ---- stage input rows [oh0-1, oh0+13] (row-clamped) for CHB channels ----
    const float* __restrict__ xb = x + ((size_t)b * Cn + cg * CHB) * (Hn * Wn);
    const int NF4 = CHB * ROWS * (Wn / 4);     // 1920 float4
    for (int f = tid; f < NF4; f += 256) {
        int ch  = f / (ROWS * (Wn / 4));
        int rem = f % (ROWS * (Wn / 4));
        int row = rem / (Wn / 4);
        int c4  = rem % (Wn / 4);
        int ih  = oh0 - 1 + row;
        ih = min(max(ih, 0), Hn - 1);          // clamped rows; weights mask them
        float4 v = *reinterpret_cast<const float4*>(
            xb + ((size_t)ch * Hn + ih) * Wn + c4 * 4);
        *reinterpret_cast<float4*>(&lds[ch][row][c4 * 4]) = v;
    }
    __syncthreads();

    // ---- compute: 4 pixels/thread x 9 taps x CHB channels ----
    #pragma unroll
    for (int px = 0; px < 4; ++px) {
        const int p    = tid + px * 256;
        const int oh_l = p >> 7;               // 0..7
        const int ow   = p & (Wn - 1);
        const int oh   = oh0 + oh_l;

        const float d = dmap[((size_t)b * Hn + oh) * Wn + ow];

        #pragma unroll
        for (int t = 0; t < NTAP; ++t) {
            const int ki = t / KK;
            const int kj = t % KK;

            float R  = (float)(oh - 1) + (float)ki * d;
            float Cc = (float)(ow - 1) + (float)kj * d;

            float r0f = floorf(R);
            float c0f = floorf(Cc);
            float wr = R - r0f;
            float wc = Cc - c0f;
            int r0 = (int)r0f;
            int c0 = (int)c0f;
            int r1 = r0 + 1;
            int c1 = c0 + 1;

            float vr0 = (r0 >= 0 && r0 < Hn) ? 1.0f : 0.0f;
            float vr1 = (r1 >= 0 && r1 < Hn) ? 1.0f : 0.0f;
            float vc0 = (c0 >= 0 && c0 < Wn) ? 1.0f : 0.0f;
            float vc1 = (c1 >= 0 && c1 < Wn) ? 1.0f : 0.0f;

            int r0c = min(max(r0, 0), Hn - 1);
            int r1c = min(max(r1, 0), Hn - 1);
            int c0c = min(max(c0, 0), Wn - 1);
            int c1c = min(max(c1, 0), Wn - 1);

            float w00 = (1.0f - wr) * (1.0f - wc) * vr0 * vc0;
            float w01 = (1.0f - wr) * wc          * vr0 * vc1;
            float w10 = wr          * (1.0f - wc) * vr1 * vc0;
            float w11 = wr          * wc          * vr1 * vc1;

            // LDS-local row indices (staged range starts at oh0-1)
            const int l0 = r0c - oh0 + 1;      // in [0, 14]
            const int l1 = r1c - oh0 + 1;      // in [0, 14]

            #pragma unroll
            for (int ch = 0; ch < CHB; ++ch) {
                float v = w00 * lds[ch][l0][c0c] + w01 * lds[ch][l0][c1c]
                        + w10 * lds[ch][l1][c0c] + w11 * lds[ch][l1][c1c];
                float* dst = out
                    + ((size_t)b * Cn * NTAP + (size_t)(cg * CHB + ch) * NTAP + t)
                        * (size_t)(Hn * Wn)
                    + (size_t)oh * Wn + ow;
                *dst = v;   // normal store: let L2/MALL write-combine and drain
            }
        }
    }
}

extern "C" void kernel_launch(void* const* d_in, const int* in_sizes, int n_in,
                              void* d_out, int out_size, void* d_ws, size_t ws_size,
                              hipStream_t stream) {
    const float* x    = (const float*)d_in[0];
    const float* dmap = (const float*)d_in[1];
    float* out = (float*)d_out;

    const int grid  = Bn * NBANDS * NCG;   // 8*16*16 = 2048 blocks
    const int block = 256;
    dyn_unfold_kernel<<<grid, block, 0, stream>>>(x, dmap, out);
}

// Round 5
// 68.216 us; speedup vs baseline: 1.0803x; 1.0803x over previous
//
#include <hip/hip_runtime.h>

// Problem constants (match reference file)
#define KK   3
#define Bn   8
#define Cn   64
#define Hn   128
#define Wn   128
#define NTAP 9

// Blocking
#define BAND  8                 // output rows per block
#define CHB   4                 // channels per block
#define ROWS  15                // BAND-1 + floor(2*3.0) + 1 (bilinear r1)
#define NBANDS (Hn / BAND)      // 16
#define NCG    (Cn / CHB)       // 16

__global__ __launch_bounds__(256) void dyn_unfold_kernel(
    const float* __restrict__ x,      // (B, C, H, W)
    const float* __restrict__ dmap,   // (B, 1, H, W)
    float* __restrict__ out)          // (B, C*9, H*W)
{
    // channel-interleaved: one float4 cell = 4 channels at (row,col)
    __shared__ float4 lds4[ROWS * Wn];     // 15*128*16B = 30 KB

    const int bid  = blockIdx.x;
    const int cg   = bid & (NCG - 1);          // channel group (fastest)
    const int band = (bid >> 4) & (NBANDS - 1);
    const int b    = bid >> 8;

    const int oh0 = band * BAND;
    const int tid = threadIdx.x;

    // ---- stage rows [oh0-1, oh0+13] (row-clamped), transposed to ch-fast ----
    // Each thread: 4 coalesced scalar loads (one per channel, same row/col),
    // then one conflict-free ds_write_b128.
    const float* __restrict__ xb = x + ((size_t)b * Cn + cg * CHB) * (Hn * Wn);
    const int NPIX = ROWS * Wn;                // 1920
    for (int f = tid; f < NPIX; f += 256) {
        int row = f >> 7;                      // / Wn
        int col = f & (Wn - 1);
        int ih  = oh0 - 1 + row;
        ih = min(max(ih, 0), Hn - 1);          // clamped rows; weights mask them
        const float* p = xb + (size_t)ih * Wn + col;
        float4 cell;
        cell.x = p[0 * Hn * Wn];
        cell.y = p[1 * Hn * Wn];
        cell.z = p[2 * Hn * Wn];
        cell.w = p[3 * Hn * Wn];
        lds4[f] = cell;
    }
    __syncthreads();

    // ---- compute: 4 pixels/thread x 9 taps x 4 channels ----
    #pragma unroll
    for (int px = 0; px < 4; ++px) {
        const int p    = tid + px * 256;
        const int oh_l = p >> 7;               // 0..7
        const int ow   = p & (Wn - 1);
        const int oh   = oh0 + oh_l;

        const float d = dmap[((size_t)b * Hn + oh) * Wn + ow];

        // row factors (ki = 0,1,2) and col factors (kj = 0,1,2), shared by taps
        float rw0[KK], rw1[KK], cw0[KK], cw1[KK];
        int   l0[KK], l1[KK], c0i[KK], c1i[KK];
        #pragma unroll
        for (int k = 0; k < KK; ++k) {
            // rows
            float R   = (float)(oh - 1) + (float)k * d;
            float r0f = floorf(R);
            float wr  = R - r0f;
            int   r0  = (int)r0f;
            int   r1  = r0 + 1;
            float vr0 = (r0 >= 0 && r0 < Hn) ? 1.0f : 0.0f;
            float vr1 = (r1 >= 0 && r1 < Hn) ? 1.0f : 0.0f;
            int   r0c = min(max(r0, 0), Hn - 1);
            int   r1c = min(max(r1, 0), Hn - 1);
            rw0[k] = (1.0f - wr) * vr0;
            rw1[k] = wr * vr1;
            l0[k]  = r0c - oh0 + 1;            // LDS-local row in [0,14]
            l1[k]  = r1c - oh0 + 1;
            // cols
            float Cc  = (float)(ow - 1) + (float)k * d;
            float c0f = floorf(Cc);
            float wc  = Cc - c0f;
            int   c0  = (int)c0f;
            int   c1  = c0 + 1;
            float vc0 = (c0 >= 0 && c0 < Wn) ? 1.0f : 0.0f;
            float vc1 = (c1 >= 0 && c1 < Wn) ? 1.0f : 0.0f;
            cw0[k] = (1.0f - wc) * vc0;
            cw1[k] = wc * vc1;
            c0i[k] = min(max(c0, 0), Wn - 1);
            c1i[k] = min(max(c1, 0), Wn - 1);
        }

        float* ob = out + ((size_t)b * Cn + cg * CHB) * (size_t)(NTAP * Hn * Wn)
                        + (size_t)oh * Wn + ow;

        #pragma unroll
        for (int ki = 0; ki < KK; ++ki) {
            #pragma unroll
            for (int kj = 0; kj < KK; ++kj) {
                const int t = ki * KK + kj;
                float w00 = rw0[ki] * cw0[kj];
                float w01 = rw0[ki] * cw1[kj];
                float w10 = rw1[ki] * cw0[kj];
                float w11 = rw1[ki] * cw1[kj];

                float4 a00 = lds4[l0[ki] * Wn + c0i[kj]];
                float4 a01 = lds4[l0[ki] * Wn + c1i[kj]];
                float4 a10 = lds4[l1[ki] * Wn + c0i[kj]];
                float4 a11 = lds4[l1[ki] * Wn + c1i[kj]];

                #pragma unroll
                for (int ch = 0; ch < CHB; ++ch) {
                    float v = w00 * (&a00.x)[ch] + w01 * (&a01.x)[ch]
                            + w10 * (&a10.x)[ch] + w11 * (&a11.x)[ch];
                    __builtin_nontemporal_store(
                        v, ob + ((size_t)ch * NTAP + t) * (size_t)(Hn * Wn));
                }
            }
        }
    }
}

extern "C" void kernel_launch(void* const* d_in, const int* in_sizes, int n_in,
                              void* d_out, int out_size, void* d_ws, size_t ws_size,
                              hipStream_t stream) {
    const float* x    = (const float*)d_in[0];
    const float* dmap = (const float*)d_in[1];
    float* out = (float*)d_out;

    const int grid  = Bn * NBANDS * NCG;   // 8*16*16 = 2048 blocks
    const int block = 256;
    dyn_unfold_kernel<<<grid, block, 0, stream>>>(x, dmap, out);
}